// Round 1
// baseline (912.888 us; speedup 1.0000x reference)
//
#include <hip/hip_runtime.h>

#define HDIM 128
#define GCOUNT 64

// ---------------- degree / CSR build ----------------

__global__ void hist_kernel(const int* __restrict__ dst, int* __restrict__ cnt, int E) {
  int e = blockIdx.x * blockDim.x + threadIdx.x;
  if (e < E) atomicAdd(&cnt[dst[e]], 1);
}

__global__ void dinv_kernel(const int* __restrict__ cnt, float* __restrict__ dinv, int n) {
  int i = blockIdx.x * blockDim.x + threadIdx.x;
  if (i < n) dinv[i] = rsqrtf((float)cnt[i] + 1.0f);
}

__global__ void scan1(const int* __restrict__ cnt, int* __restrict__ row_ptr,
                      int* __restrict__ bsum, int n) {
  __shared__ int sh[256];
  int t = threadIdx.x;
  int i = blockIdx.x * 256 + t;
  int v = (i < n) ? cnt[i] : 0;
  sh[t] = v;
  __syncthreads();
  for (int off = 1; off < 256; off <<= 1) {
    int u = (t >= off) ? sh[t - off] : 0;
    __syncthreads();
    sh[t] += u;
    __syncthreads();
  }
  if (i < n) row_ptr[i] = sh[t] - v;          // exclusive within block
  if (t == 255) bsum[blockIdx.x] = sh[255];   // block total
}

__global__ void scan2(int* __restrict__ bsum, int nb) {
  __shared__ int sh[512];
  int t = threadIdx.x;
  int v = (t < nb) ? bsum[t] : 0;
  sh[t] = v;
  __syncthreads();
  for (int off = 1; off < 512; off <<= 1) {
    int u = (t >= off) ? sh[t - off] : 0;
    __syncthreads();
    sh[t] += u;
    __syncthreads();
  }
  if (t < nb) bsum[t] = sh[t] - v;            // exclusive block offsets
}

__global__ void scan3(int* __restrict__ row_ptr, const int* __restrict__ bsum,
                      int* __restrict__ cur, int n, int E) {
  int i = blockIdx.x * blockDim.x + threadIdx.x;
  if (i < n) {
    int r = row_ptr[i] + bsum[i >> 8];
    row_ptr[i] = r;
    cur[i] = r;
  }
  if (i == 0) row_ptr[n] = E;
}

__global__ void fill_kernel(const int* __restrict__ src, const int* __restrict__ dst,
                            int* __restrict__ cur, int* __restrict__ col, int E) {
  int e = blockIdx.x * blockDim.x + threadIdx.x;
  if (e < E) {
    int slot = atomicAdd(&cur[dst[e]], 1);
    col[slot] = src[e];
  }
}

// ---------------- aggregation: out[i] = dinv_i^2 x_i + sum_{j->i} dinv_i dinv_j x_j -------
// One 32-lane group per dst row; each lane owns one float4 (4 of 128 cols).

__global__ void agg_kernel(const float* __restrict__ X, const float* __restrict__ dinv,
                           const int* __restrict__ row_ptr, const int* __restrict__ col,
                           float* __restrict__ out, int n) {
  int g = (blockIdx.x * blockDim.x + threadIdx.x) >> 5;
  int lane = threadIdx.x & 31;
  if (g >= n) return;
  float di = dinv[g];
  float4 xv = ((const float4*)X)[(size_t)g * 32 + lane];
  float c = di * di;
  float4 acc = make_float4(c * xv.x, c * xv.y, c * xv.z, c * xv.w);
  int e0 = row_ptr[g], e1 = row_ptr[g + 1];
  for (int e = e0; e < e1; e++) {
    int s = col[e];
    float cs = di * dinv[s];
    float4 v = ((const float4*)X)[(size_t)s * 32 + lane];
    acc.x += cs * v.x; acc.y += cs * v.y; acc.z += cs * v.z; acc.w += cs * v.w;
  }
  ((float4*)out)[(size_t)g * 32 + lane] = acc;
}

// ---------------- GEMM: Y = relu(A @ W + b), A [n,128], W [128,128] -------------
// 64 rows/block, 256 threads; thread = 4 rows x 8 cols (cols cg*4 and 64+cg*4).
// K staged in 4 chunks of 32; LDS ~26 KB.

__global__ __launch_bounds__(256) void gemm_bias_relu(
    const float* __restrict__ A, const float* __restrict__ W,
    const float* __restrict__ bias, float* __restrict__ Y, int n) {
  __shared__ float As[64 * 36];    // 64 rows x 32 k, padded stride 36
  __shared__ float Ws[32 * 132];   // 32 k x 128 cols, padded stride 132
  int t = threadIdx.x;
  int row0 = blockIdx.x << 6;
  int rg = t >> 4;       // rows rg*4 .. rg*4+3
  int cg = t & 15;       // cols cg*4..+3 and 64+cg*4..+3
  float acc[4][8];
  #pragma unroll
  for (int r = 0; r < 4; r++)
    #pragma unroll
    for (int c = 0; c < 8; c++) acc[r][c] = 0.f;

  for (int kb = 0; kb < 4; kb++) {
    __syncthreads();
    for (int i = t; i < 512; i += 256) {           // A chunk: 64 rows x 8 f4
      int r = i >> 3, q = i & 7;
      int gr = row0 + r;
      float4 v = make_float4(0.f, 0.f, 0.f, 0.f);
      if (gr < n) v = ((const float4*)A)[(size_t)gr * 32 + kb * 8 + q];
      *(float4*)&As[r * 36 + q * 4] = v;
    }
    for (int i = t; i < 1024; i += 256) {          // W chunk: 32 k x 32 f4
      int r = i >> 5, q = i & 31;
      *(float4*)&Ws[r * 132 + q * 4] = ((const float4*)W)[(size_t)(kb * 32 + r) * 32 + q];
    }
    __syncthreads();
    #pragma unroll
    for (int k = 0; k < 32; k += 4) {
      float4 a0 = *(const float4*)&As[(rg * 4 + 0) * 36 + k];
      float4 a1 = *(const float4*)&As[(rg * 4 + 1) * 36 + k];
      float4 a2 = *(const float4*)&As[(rg * 4 + 2) * 36 + k];
      float4 a3 = *(const float4*)&As[(rg * 4 + 3) * 36 + k];
      #pragma unroll
      for (int kk = 0; kk < 4; kk++) {
        float4 w0 = *(const float4*)&Ws[(k + kk) * 132 + cg * 4];
        float4 w1 = *(const float4*)&Ws[(k + kk) * 132 + 64 + cg * 4];
        float av0 = kk == 0 ? a0.x : kk == 1 ? a0.y : kk == 2 ? a0.z : a0.w;
        float av1 = kk == 0 ? a1.x : kk == 1 ? a1.y : kk == 2 ? a1.z : a1.w;
        float av2 = kk == 0 ? a2.x : kk == 1 ? a2.y : kk == 2 ? a2.z : a2.w;
        float av3 = kk == 0 ? a3.x : kk == 1 ? a3.y : kk == 2 ? a3.z : a3.w;
        acc[0][0] += av0 * w0.x; acc[0][1] += av0 * w0.y; acc[0][2] += av0 * w0.z; acc[0][3] += av0 * w0.w;
        acc[0][4] += av0 * w1.x; acc[0][5] += av0 * w1.y; acc[0][6] += av0 * w1.z; acc[0][7] += av0 * w1.w;
        acc[1][0] += av1 * w0.x; acc[1][1] += av1 * w0.y; acc[1][2] += av1 * w0.z; acc[1][3] += av1 * w0.w;
        acc[1][4] += av1 * w1.x; acc[1][5] += av1 * w1.y; acc[1][6] += av1 * w1.z; acc[1][7] += av1 * w1.w;
        acc[2][0] += av2 * w0.x; acc[2][1] += av2 * w0.y; acc[2][2] += av2 * w0.z; acc[2][3] += av2 * w0.w;
        acc[2][4] += av2 * w1.x; acc[2][5] += av2 * w1.y; acc[2][6] += av2 * w1.z; acc[2][7] += av2 * w1.w;
        acc[3][0] += av3 * w0.x; acc[3][1] += av3 * w0.y; acc[3][2] += av3 * w0.z; acc[3][3] += av3 * w0.w;
        acc[3][4] += av3 * w1.x; acc[3][5] += av3 * w1.y; acc[3][6] += av3 * w1.z; acc[3][7] += av3 * w1.w;
      }
    }
  }
  float4 b0v = *(const float4*)&bias[cg * 4];
  float4 b1v = *(const float4*)&bias[64 + cg * 4];
  #pragma unroll
  for (int r = 0; r < 4; r++) {
    int gr = row0 + rg * 4 + r;
    if (gr < n) {
      float4 o0 = make_float4(fmaxf(acc[r][0] + b0v.x, 0.f), fmaxf(acc[r][1] + b0v.y, 0.f),
                              fmaxf(acc[r][2] + b0v.z, 0.f), fmaxf(acc[r][3] + b0v.w, 0.f));
      float4 o1 = make_float4(fmaxf(acc[r][4] + b1v.x, 0.f), fmaxf(acc[r][5] + b1v.y, 0.f),
                              fmaxf(acc[r][6] + b1v.z, 0.f), fmaxf(acc[r][7] + b1v.w, 0.f));
      ((float4*)Y)[(size_t)gr * 32 + cg] = o0;
      ((float4*)Y)[(size_t)gr * 32 + 16 + cg] = o1;
    }
  }
}

// ---------------- mean pool (batch sorted) ----------------

__global__ void pool_kernel(const float* __restrict__ X, const int* __restrict__ batch,
                            float* __restrict__ pooled, float* __restrict__ gcnt, int n) {
  int t = threadIdx.x;             // 128 threads = columns
  int r0 = blockIdx.x * 64;
  if (r0 >= n) return;
  int r1 = min(r0 + 64, n);
  int g = batch[r0];
  float acc = 0.f, cl = 0.f;
  for (int r = r0; r < r1; r++) {
    int gr = batch[r];
    if (gr != g) {
      atomicAdd(&pooled[g * HDIM + t], acc);
      if (t == 0) atomicAdd(&gcnt[g], cl);
      acc = 0.f; cl = 0.f; g = gr;
    }
    acc += X[(size_t)r * HDIM + t];
    cl += 1.f;
  }
  atomicAdd(&pooled[g * HDIM + t], acc);
  if (t == 0) atomicAdd(&gcnt[g], cl);
}

// ---------------- classifier head ----------------
// combined = [p, p] -> h = relu(p @ (Wc1_top + Wc1_bot) + bc1); out = h @ Wc2 + bc2

__global__ void cls_kernel(const float* __restrict__ pooled, const float* __restrict__ gcnt,
                           const float* __restrict__ Wc1, const float* __restrict__ bc1,
                           const float* __restrict__ Wc2, const float* __restrict__ bc2,
                           float* __restrict__ out) {
  __shared__ float p[HDIM];
  __shared__ float r0s[HDIM], r1s[HDIM];
  int g = blockIdx.x, t = threadIdx.x;
  float c = fmaxf(gcnt[g], 1.0f);
  p[t] = pooled[g * HDIM + t] / c;
  __syncthreads();
  float acc = bc1[t];
  for (int k = 0; k < HDIM; k++) {
    acc += p[k] * (Wc1[k * HDIM + t] + Wc1[(HDIM + k) * HDIM + t]);
  }
  float h = fmaxf(acc, 0.f);
  r0s[t] = h * Wc2[t * 2 + 0];
  r1s[t] = h * Wc2[t * 2 + 1];
  __syncthreads();
  for (int s2 = 64; s2 > 0; s2 >>= 1) {
    if (t < s2) { r0s[t] += r0s[t + s2]; r1s[t] += r1s[t + s2]; }
    __syncthreads();
  }
  if (t == 0) {
    out[g * 2 + 0] = r0s[0] + bc2[0];
    out[g * 2 + 1] = r1s[0] + bc2[1];
  }
}

// ---------------- launch ----------------

extern "C" void kernel_launch(void* const* d_in, const int* in_sizes, int n_in,
                              void* d_out, int out_size, void* d_ws, size_t ws_size,
                              hipStream_t stream) {
  const float* x   = (const float*)d_in[0];
  const int*   ei  = (const int*)d_in[1];
  const int*   bat = (const int*)d_in[2];
  const float* W0  = (const float*)d_in[3];
  const float* b0  = (const float*)d_in[4];
  const float* W1  = (const float*)d_in[5];
  const float* b1  = (const float*)d_in[6];
  const float* W2  = (const float*)d_in[7];
  const float* b2  = (const float*)d_in[8];
  const float* Wc1 = (const float*)d_in[9];
  const float* bc1 = (const float*)d_in[10];
  const float* Wc2 = (const float*)d_in[11];
  const float* bc2 = (const float*)d_in[12];
  float* out = (float*)d_out;

  int N = in_sizes[0] / HDIM;
  int E = in_sizes[1] / 2;
  const int* src = ei;
  const int* dst = ei + E;

  char* ws = (char*)d_ws;
  size_t off = 0;
  auto alloc = [&](size_t bytes) -> void* {
    void* p = (void*)(ws + off);
    off += (bytes + 511) & ~(size_t)511;
    return p;
  };
  float* bufA   = (float*)alloc((size_t)N * HDIM * 4);
  float* bufB   = (float*)alloc((size_t)N * HDIM * 4);
  float* dinv   = (float*)alloc((size_t)N * 4);
  int*   cnt    = (int*)alloc((size_t)N * 4);
  int*   rowp   = (int*)alloc((size_t)(N + 1) * 4);
  int*   cur    = (int*)alloc((size_t)N * 4);
  int*   col    = (int*)alloc((size_t)E * 4);
  float* pooled = (float*)alloc((size_t)GCOUNT * HDIM * 4);
  float* gcnt   = (float*)alloc((size_t)GCOUNT * 4);
  int nb = (N + 255) / 256;
  int*   bsum   = (int*)alloc((size_t)nb * 4);

  hipMemsetAsync(cnt, 0, (size_t)N * 4, stream);
  hipMemsetAsync(pooled, 0, (size_t)GCOUNT * HDIM * 4, stream);
  hipMemsetAsync(gcnt, 0, (size_t)GCOUNT * 4, stream);

  hist_kernel<<<(E + 255) / 256, 256, 0, stream>>>(dst, cnt, E);
  dinv_kernel<<<(N + 255) / 256, 256, 0, stream>>>(cnt, dinv, N);
  scan1<<<nb, 256, 0, stream>>>(cnt, rowp, bsum, N);
  scan2<<<1, 512, 0, stream>>>(bsum, nb);
  scan3<<<(N + 255) / 256, 256, 0, stream>>>(rowp, bsum, cur, N, E);
  fill_kernel<<<(E + 255) / 256, 256, 0, stream>>>(src, dst, cur, col, E);

  int aggBlocks = (int)(((size_t)N * 32 + 255) / 256);
  int gemmBlocks = (N + 63) / 64;

  agg_kernel<<<aggBlocks, 256, 0, stream>>>(x, dinv, rowp, col, bufA, N);
  gemm_bias_relu<<<gemmBlocks, 256, 0, stream>>>(bufA, W0, b0, bufB, N);

  agg_kernel<<<aggBlocks, 256, 0, stream>>>(bufB, dinv, rowp, col, bufA, N);
  gemm_bias_relu<<<gemmBlocks, 256, 0, stream>>>(bufA, W1, b1, bufB, N);

  agg_kernel<<<aggBlocks, 256, 0, stream>>>(bufB, dinv, rowp, col, bufA, N);
  gemm_bias_relu<<<gemmBlocks, 256, 0, stream>>>(bufA, W2, b2, bufB, N);

  pool_kernel<<<(N + 63) / 64, 128, 0, stream>>>(bufB, bat, pooled, gcnt, N);
  cls_kernel<<<GCOUNT, HDIM, 0, stream>>>(pooled, gcnt, Wc1, bc1, Wc2, bc2, out);
}

// Round 2
// 726.900 us; speedup vs baseline: 1.2559x; 1.2559x over previous
//
#include <hip/hip_runtime.h>

#define HDIM 128
#define GCOUNT 64

// ---- bf16 helpers (manual, RNE) ----
__device__ __forceinline__ float bfl(unsigned u) { return __uint_as_float(u << 16); }
__device__ __forceinline__ float bfh(unsigned u) { return __uint_as_float(u & 0xffff0000u); }
__device__ __forceinline__ unsigned short f2bf(float f) {
  unsigned u = __float_as_uint(f);
  unsigned r = (u + 0x7fffu + ((u >> 16) & 1u)) >> 16;
  return (unsigned short)r;
}
__device__ __forceinline__ unsigned pk2(float a, float b) {
  return (unsigned)f2bf(a) | ((unsigned)f2bf(b) << 16);
}

// ---------------- degree / CSR build ----------------

__global__ void hist_kernel(const int* __restrict__ dst, int* __restrict__ cnt, int E) {
  int e = blockIdx.x * blockDim.x + threadIdx.x;
  if (e < E) atomicAdd(&cnt[dst[e]], 1);
}

__global__ void dinv_kernel(const int* __restrict__ cnt, float* __restrict__ dinv, int n) {
  int i = blockIdx.x * blockDim.x + threadIdx.x;
  if (i < n) dinv[i] = rsqrtf((float)cnt[i] + 1.0f);
}

__global__ void scan1(const int* __restrict__ cnt, int* __restrict__ row_ptr,
                      int* __restrict__ bsum, int n) {
  __shared__ int sh[256];
  int t = threadIdx.x;
  int i = blockIdx.x * 256 + t;
  int v = (i < n) ? cnt[i] : 0;
  sh[t] = v;
  __syncthreads();
  for (int off = 1; off < 256; off <<= 1) {
    int u = (t >= off) ? sh[t - off] : 0;
    __syncthreads();
    sh[t] += u;
    __syncthreads();
  }
  if (i < n) row_ptr[i] = sh[t] - v;
  if (t == 255) bsum[blockIdx.x] = sh[255];
}

__global__ void scan2(int* __restrict__ bsum, int nb) {
  __shared__ int sh[512];
  int t = threadIdx.x;
  int v = (t < nb) ? bsum[t] : 0;
  sh[t] = v;
  __syncthreads();
  for (int off = 1; off < 512; off <<= 1) {
    int u = (t >= off) ? sh[t - off] : 0;
    __syncthreads();
    sh[t] += u;
    __syncthreads();
  }
  if (t < nb) bsum[t] = sh[t] - v;
}

__global__ void scan3(int* __restrict__ row_ptr, const int* __restrict__ bsum,
                      int* __restrict__ cur, int n, int E) {
  int i = blockIdx.x * blockDim.x + threadIdx.x;
  if (i < n) {
    int r = row_ptr[i] + bsum[i >> 8];
    row_ptr[i] = r;
    cur[i] = r;
  }
  if (i == 0) row_ptr[n] = E;
}

__global__ void fill_kernel(const int* __restrict__ src, const int* __restrict__ dst,
                            int* __restrict__ cur, int* __restrict__ col, int E) {
  int e = blockIdx.x * blockDim.x + threadIdx.x;
  if (e < E) {
    int slot = atomicAdd(&cur[dst[e]], 1);
    col[slot] = src[e];
  }
}

// ---------------- prescale: S0[i] = bf16(dinv_i * x_i) ----------------

__global__ void prescale_kernel(const float* __restrict__ x, const float* __restrict__ dinv,
                                unsigned short* __restrict__ S, int n4) {
  int i = blockIdx.x * blockDim.x + threadIdx.x;
  if (i >= n4) return;
  float4 v = ((const float4*)x)[i];
  float d = dinv[i >> 5];
  ushort4 o;
  o.x = f2bf(v.x * d); o.y = f2bf(v.y * d); o.z = f2bf(v.z * d); o.w = f2bf(v.w * d);
  ((ushort4*)S)[i] = o;
}

// ---------------- aggregation (scaled bf16 state) ----------------
// S holds s_i = dinv_i * h_i (bf16, row = 16 uint4). out_i = dinv_i*(s_i + sum_{j->i} s_j),
// written as bf16. One 16-lane group per row; lane owns 8 bf16 (one uint4).

__global__ void agg_bf16(const uint4* __restrict__ S, const float* __restrict__ dinv,
                         const int* __restrict__ rowp, const int* __restrict__ col,
                         uint4* __restrict__ OUT, int n) {
  int g = (blockIdx.x * blockDim.x + threadIdx.x) >> 4;
  int lane = threadIdx.x & 15;
  if (g >= n) return;
  uint4 u = S[(size_t)g * 16 + lane];
  float a0 = bfl(u.x), a1 = bfh(u.x), a2 = bfl(u.y), a3 = bfh(u.y);
  float a4 = bfl(u.z), a5 = bfh(u.z), a6 = bfl(u.w), a7 = bfh(u.w);
  int e0 = rowp[g], e1 = rowp[g + 1];
  for (int e = e0; e < e1; e++) {
    int s = col[e];
    uint4 v = S[(size_t)s * 16 + lane];
    a0 += bfl(v.x); a1 += bfh(v.x); a2 += bfl(v.y); a3 += bfh(v.y);
    a4 += bfl(v.z); a5 += bfh(v.z); a6 += bfl(v.w); a7 += bfh(v.w);
  }
  float d = dinv[g];
  uint4 o;
  o.x = pk2(a0 * d, a1 * d); o.y = pk2(a2 * d, a3 * d);
  o.z = pk2(a4 * d, a5 * d); o.w = pk2(a6 * d, a7 * d);
  OUT[(size_t)g * 16 + lane] = o;
}

// ---------------- GEMM: Y = relu(A @ W + b) [* dinv if do_scale], A bf16 [n,128] ----------
// 64 rows/block, 256 threads; thread = 4 rows x 8 cols. K in 4 chunks of 32. f32 compute.

__global__ __launch_bounds__(256) void gemm_bias_relu(
    const uint4* __restrict__ A, const float* __restrict__ W,
    const float* __restrict__ bias, const float* __restrict__ dinv, int do_scale,
    unsigned short* __restrict__ Y, int n) {
  __shared__ float As[64 * 36];    // 64 rows x 32 k, stride 36
  __shared__ float Ws[32 * 132];   // 32 k x 128 cols, stride 132
  int t = threadIdx.x;
  int row0 = blockIdx.x << 6;
  int rg = t >> 4;
  int cg = t & 15;
  float acc[4][8];
  #pragma unroll
  for (int r = 0; r < 4; r++)
    #pragma unroll
    for (int c = 0; c < 8; c++) acc[r][c] = 0.f;

  for (int kb = 0; kb < 4; kb++) {
    __syncthreads();
    {                                     // A chunk: 64 rows x 32 bf16 (4 uint4 per row)
      int r = t >> 2, q = t & 3;
      int gr = row0 + r;
      uint4 v = make_uint4(0, 0, 0, 0);
      if (gr < n) v = A[(size_t)gr * 16 + kb * 4 + q];
      float4 f0 = make_float4(bfl(v.x), bfh(v.x), bfl(v.y), bfh(v.y));
      float4 f1 = make_float4(bfl(v.z), bfh(v.z), bfl(v.w), bfh(v.w));
      *(float4*)&As[r * 36 + q * 8] = f0;
      *(float4*)&As[r * 36 + q * 8 + 4] = f1;
    }
    for (int i = t; i < 1024; i += 256) { // W chunk: 32 k x 32 f4
      int r = i >> 5, q = i & 31;
      *(float4*)&Ws[r * 132 + q * 4] = ((const float4*)W)[(size_t)(kb * 32 + r) * 32 + q];
    }
    __syncthreads();
    #pragma unroll
    for (int k = 0; k < 32; k += 4) {
      float4 a0 = *(const float4*)&As[(rg * 4 + 0) * 36 + k];
      float4 a1 = *(const float4*)&As[(rg * 4 + 1) * 36 + k];
      float4 a2 = *(const float4*)&As[(rg * 4 + 2) * 36 + k];
      float4 a3 = *(const float4*)&As[(rg * 4 + 3) * 36 + k];
      #pragma unroll
      for (int kk = 0; kk < 4; kk++) {
        float4 w0 = *(const float4*)&Ws[(k + kk) * 132 + cg * 4];
        float4 w1 = *(const float4*)&Ws[(k + kk) * 132 + 64 + cg * 4];
        float av0 = kk == 0 ? a0.x : kk == 1 ? a0.y : kk == 2 ? a0.z : a0.w;
        float av1 = kk == 0 ? a1.x : kk == 1 ? a1.y : kk == 2 ? a1.z : a1.w;
        float av2 = kk == 0 ? a2.x : kk == 1 ? a2.y : kk == 2 ? a2.z : a2.w;
        float av3 = kk == 0 ? a3.x : kk == 1 ? a3.y : kk == 2 ? a3.z : a3.w;
        acc[0][0] += av0 * w0.x; acc[0][1] += av0 * w0.y; acc[0][2] += av0 * w0.z; acc[0][3] += av0 * w0.w;
        acc[0][4] += av0 * w1.x; acc[0][5] += av0 * w1.y; acc[0][6] += av0 * w1.z; acc[0][7] += av0 * w1.w;
        acc[1][0] += av1 * w0.x; acc[1][1] += av1 * w0.y; acc[1][2] += av1 * w0.z; acc[1][3] += av1 * w0.w;
        acc[1][4] += av1 * w1.x; acc[1][5] += av1 * w1.y; acc[1][6] += av1 * w1.z; acc[1][7] += av1 * w1.w;
        acc[2][0] += av2 * w0.x; acc[2][1] += av2 * w0.y; acc[2][2] += av2 * w0.z; acc[2][3] += av2 * w0.w;
        acc[2][4] += av2 * w1.x; acc[2][5] += av2 * w1.y; acc[2][6] += av2 * w1.z; acc[2][7] += av2 * w1.w;
        acc[3][0] += av3 * w0.x; acc[3][1] += av3 * w0.y; acc[3][2] += av3 * w0.z; acc[3][3] += av3 * w0.w;
        acc[3][4] += av3 * w1.x; acc[3][5] += av3 * w1.y; acc[3][6] += av3 * w1.z; acc[3][7] += av3 * w1.w;
      }
    }
  }
  float4 b0v = *(const float4*)&bias[cg * 4];
  float4 b1v = *(const float4*)&bias[64 + cg * 4];
  #pragma unroll
  for (int r = 0; r < 4; r++) {
    int gr = row0 + rg * 4 + r;
    if (gr < n) {
      float sc = do_scale ? dinv[gr] : 1.0f;
      float o0 = fmaxf(acc[r][0] + b0v.x, 0.f) * sc;
      float o1 = fmaxf(acc[r][1] + b0v.y, 0.f) * sc;
      float o2 = fmaxf(acc[r][2] + b0v.z, 0.f) * sc;
      float o3 = fmaxf(acc[r][3] + b0v.w, 0.f) * sc;
      float o4 = fmaxf(acc[r][4] + b1v.x, 0.f) * sc;
      float o5 = fmaxf(acc[r][5] + b1v.y, 0.f) * sc;
      float o6 = fmaxf(acc[r][6] + b1v.z, 0.f) * sc;
      float o7 = fmaxf(acc[r][7] + b1v.w, 0.f) * sc;
      ushort4 p0; p0.x = f2bf(o0); p0.y = f2bf(o1); p0.z = f2bf(o2); p0.w = f2bf(o3);
      ushort4 p1; p1.x = f2bf(o4); p1.y = f2bf(o5); p1.z = f2bf(o6); p1.w = f2bf(o7);
      ((ushort4*)Y)[(size_t)gr * 32 + cg] = p0;
      ((ushort4*)Y)[(size_t)gr * 32 + 16 + cg] = p1;
    }
  }
}

// ---------------- mean pool (batch sorted, bf16 input) ----------------

__global__ void pool_kernel(const unsigned short* __restrict__ X, const int* __restrict__ batch,
                            float* __restrict__ pooled, float* __restrict__ gcnt, int n) {
  int t = threadIdx.x;             // 128 threads = columns
  int r0 = blockIdx.x * 64;
  if (r0 >= n) return;
  int r1 = min(r0 + 64, n);
  int g = batch[r0];
  float acc = 0.f, cl = 0.f;
  for (int r = r0; r < r1; r++) {
    int gr = batch[r];
    if (gr != g) {
      atomicAdd(&pooled[g * HDIM + t], acc);
      if (t == 0) atomicAdd(&gcnt[g], cl);
      acc = 0.f; cl = 0.f; g = gr;
    }
    acc += __uint_as_float((unsigned)X[(size_t)r * HDIM + t] << 16);
    cl += 1.f;
  }
  atomicAdd(&pooled[g * HDIM + t], acc);
  if (t == 0) atomicAdd(&gcnt[g], cl);
}

// ---------------- classifier head ----------------

__global__ void cls_kernel(const float* __restrict__ pooled, const float* __restrict__ gcnt,
                           const float* __restrict__ Wc1, const float* __restrict__ bc1,
                           const float* __restrict__ Wc2, const float* __restrict__ bc2,
                           float* __restrict__ out) {
  __shared__ float p[HDIM];
  __shared__ float r0s[HDIM], r1s[HDIM];
  int g = blockIdx.x, t = threadIdx.x;
  float c = fmaxf(gcnt[g], 1.0f);
  p[t] = pooled[g * HDIM + t] / c;
  __syncthreads();
  float acc = bc1[t];
  for (int k = 0; k < HDIM; k++) {
    acc += p[k] * (Wc1[k * HDIM + t] + Wc1[(HDIM + k) * HDIM + t]);
  }
  float h = fmaxf(acc, 0.f);
  r0s[t] = h * Wc2[t * 2 + 0];
  r1s[t] = h * Wc2[t * 2 + 1];
  __syncthreads();
  for (int s2 = 64; s2 > 0; s2 >>= 1) {
    if (t < s2) { r0s[t] += r0s[t + s2]; r1s[t] += r1s[t + s2]; }
    __syncthreads();
  }
  if (t == 0) {
    out[g * 2 + 0] = r0s[0] + bc2[0];
    out[g * 2 + 1] = r1s[0] + bc2[1];
  }
}

// ---------------- launch ----------------

extern "C" void kernel_launch(void* const* d_in, const int* in_sizes, int n_in,
                              void* d_out, int out_size, void* d_ws, size_t ws_size,
                              hipStream_t stream) {
  const float* x   = (const float*)d_in[0];
  const int*   ei  = (const int*)d_in[1];
  const int*   bat = (const int*)d_in[2];
  const float* W0  = (const float*)d_in[3];
  const float* b0  = (const float*)d_in[4];
  const float* W1  = (const float*)d_in[5];
  const float* b1  = (const float*)d_in[6];
  const float* W2  = (const float*)d_in[7];
  const float* b2  = (const float*)d_in[8];
  const float* Wc1 = (const float*)d_in[9];
  const float* bc1 = (const float*)d_in[10];
  const float* Wc2 = (const float*)d_in[11];
  const float* bc2 = (const float*)d_in[12];
  float* out = (float*)d_out;

  int N = in_sizes[0] / HDIM;
  int E = in_sizes[1] / 2;
  const int* src = ei;
  const int* dst = ei + E;

  char* ws = (char*)d_ws;
  size_t off = 0;
  auto alloc = [&](size_t bytes) -> void* {
    void* p = (void*)(ws + off);
    off += (bytes + 511) & ~(size_t)511;
    return p;
  };
  unsigned short* bufS = (unsigned short*)alloc((size_t)N * HDIM * 2);  // scaled state bf16
  unsigned short* bufA = (unsigned short*)alloc((size_t)N * HDIM * 2);  // agg out bf16
  float* dinv   = (float*)alloc((size_t)N * 4);
  int*   cnt    = (int*)alloc((size_t)N * 4);
  int*   rowp   = (int*)alloc((size_t)(N + 1) * 4);
  int*   cur    = (int*)alloc((size_t)N * 4);
  int*   col    = (int*)alloc((size_t)E * 4);
  float* pooled = (float*)alloc((size_t)GCOUNT * HDIM * 4);
  float* gcnt   = (float*)alloc((size_t)GCOUNT * 4);
  int nb = (N + 255) / 256;
  int*   bsum   = (int*)alloc((size_t)nb * 4);

  hipMemsetAsync(cnt, 0, (size_t)N * 4, stream);
  hipMemsetAsync(pooled, 0, (size_t)GCOUNT * HDIM * 4, stream);
  hipMemsetAsync(gcnt, 0, (size_t)GCOUNT * 4, stream);

  hist_kernel<<<(E + 255) / 256, 256, 0, stream>>>(dst, cnt, E);
  dinv_kernel<<<(N + 255) / 256, 256, 0, stream>>>(cnt, dinv, N);
  scan1<<<nb, 256, 0, stream>>>(cnt, rowp, bsum, N);
  scan2<<<1, 512, 0, stream>>>(bsum, nb);
  scan3<<<(N + 255) / 256, 256, 0, stream>>>(rowp, bsum, cur, N, E);
  fill_kernel<<<(E + 255) / 256, 256, 0, stream>>>(src, dst, cur, col, E);

  int n4 = N * 32;
  prescale_kernel<<<(n4 + 255) / 256, 256, 0, stream>>>(x, dinv, bufS, n4);

  int aggBlocks = (int)(((size_t)N * 16 + 255) / 256);
  int gemmBlocks = (N + 63) / 64;

  agg_bf16<<<aggBlocks, 256, 0, stream>>>((const uint4*)bufS, dinv, rowp, col, (uint4*)bufA, N);
  gemm_bias_relu<<<gemmBlocks, 256, 0, stream>>>((const uint4*)bufA, W0, b0, dinv, 1, bufS, N);

  agg_bf16<<<aggBlocks, 256, 0, stream>>>((const uint4*)bufS, dinv, rowp, col, (uint4*)bufA, N);
  gemm_bias_relu<<<gemmBlocks, 256, 0, stream>>>((const uint4*)bufA, W1, b1, dinv, 1, bufS, N);

  agg_bf16<<<aggBlocks, 256, 0, stream>>>((const uint4*)bufS, dinv, rowp, col, (uint4*)bufA, N);
  gemm_bias_relu<<<gemmBlocks, 256, 0, stream>>>((const uint4*)bufA, W2, b2, dinv, 0, bufS, N);

  pool_kernel<<<(N + 63) / 64, 128, 0, stream>>>(bufS, bat, pooled, gcnt, N);
  cls_kernel<<<GCOUNT, HDIM, 0, stream>>>(pooled, gcnt, Wc1, bc1, Wc2, bc2, out);
}

// Round 3
// 688.031 us; speedup vs baseline: 1.3268x; 1.0565x over previous
//
#include <hip/hip_runtime.h>

#define HDIM 128
#define GCOUNT 64

// ---- bf16 helpers (manual, RNE) ----
__device__ __forceinline__ float bfl(unsigned u) { return __uint_as_float(u << 16); }
__device__ __forceinline__ float bfh(unsigned u) { return __uint_as_float(u & 0xffff0000u); }
__device__ __forceinline__ unsigned short f2bf(float f) {
  unsigned u = __float_as_uint(f);
  unsigned r = (u + 0x7fffu + ((u >> 16) & 1u)) >> 16;
  return (unsigned short)r;
}
__device__ __forceinline__ unsigned pk2(float a, float b) {
  return (unsigned)f2bf(a) | ((unsigned)f2bf(b) << 16);
}

// ---------------- degree / CSR build ----------------
// 8 edges per thread: issue independent atomics back-to-back for latency hiding.

__global__ void hist_kernel(const int* __restrict__ dst, int* __restrict__ cnt, int E) {
  int i0 = blockIdx.x * (blockDim.x * 8) + threadIdx.x;
  #pragma unroll
  for (int j = 0; j < 8; j++) {
    int e = i0 + j * 256;
    if (e < E) atomicAdd(&cnt[dst[e]], 1);   // no return use -> fire-and-forget
  }
}

__global__ void scan1(const int* __restrict__ cnt, int* __restrict__ row_ptr,
                      int* __restrict__ bsum, float* __restrict__ dinv, int n) {
  __shared__ int sh[256];
  int t = threadIdx.x;
  int i = blockIdx.x * 256 + t;
  int v = (i < n) ? cnt[i] : 0;
  if (i < n) dinv[i] = rsqrtf((float)v + 1.0f);
  sh[t] = v;
  __syncthreads();
  for (int off = 1; off < 256; off <<= 1) {
    int u = (t >= off) ? sh[t - off] : 0;
    __syncthreads();
    sh[t] += u;
    __syncthreads();
  }
  if (i < n) row_ptr[i] = sh[t] - v;
  if (t == 255) bsum[blockIdx.x] = sh[255];
}

__global__ void scan2(int* __restrict__ bsum, int nb) {
  __shared__ int sh[512];
  int t = threadIdx.x;
  int v = (t < nb) ? bsum[t] : 0;
  sh[t] = v;
  __syncthreads();
  for (int off = 1; off < 512; off <<= 1) {
    int u = (t >= off) ? sh[t - off] : 0;
    __syncthreads();
    sh[t] += u;
    __syncthreads();
  }
  if (t < nb) bsum[t] = sh[t] - v;
}

__global__ void scan3(int* __restrict__ row_ptr, const int* __restrict__ bsum,
                      int* __restrict__ cur, int n, int E) {
  int i = blockIdx.x * blockDim.x + threadIdx.x;
  if (i < n) {
    int r = row_ptr[i] + bsum[i >> 8];
    row_ptr[i] = r;
    cur[i] = r;
  }
  if (i == 0) row_ptr[n] = E;
}

// 8 edges/thread: all 8 atomic round-trips issued before any dependent store.
__global__ void fill_kernel(const int* __restrict__ src, const int* __restrict__ dst,
                            int* __restrict__ cur, int* __restrict__ col, int E) {
  int i0 = blockIdx.x * (blockDim.x * 8) + threadIdx.x;
  int slots[8], srcs[8];
  #pragma unroll
  for (int j = 0; j < 8; j++) {
    int e = i0 + j * 256;
    if (e < E) {
      srcs[j] = src[e];
      slots[j] = atomicAdd(&cur[dst[e]], 1);
    } else {
      slots[j] = -1;
    }
  }
  #pragma unroll
  for (int j = 0; j < 8; j++) {
    if (slots[j] >= 0) col[slots[j]] = srcs[j];
  }
}

// ---------------- prescale: S0[i] = bf16(dinv_i * x_i) ----------------

__global__ void prescale_kernel(const float* __restrict__ x, const float* __restrict__ dinv,
                                unsigned short* __restrict__ S, int n4) {
  int i = blockIdx.x * blockDim.x + threadIdx.x;
  if (i >= n4) return;
  float4 v = ((const float4*)x)[i];
  float d = dinv[i >> 5];
  ushort4 o;
  o.x = f2bf(v.x * d); o.y = f2bf(v.y * d); o.z = f2bf(v.z * d); o.w = f2bf(v.w * d);
  ((ushort4*)S)[i] = o;
}

// ---------------- aggregation (scaled bf16 state) ----------------

__global__ void agg_bf16(const uint4* __restrict__ S, const float* __restrict__ dinv,
                         const int* __restrict__ rowp, const int* __restrict__ col,
                         uint4* __restrict__ OUT, int n) {
  int g = (blockIdx.x * blockDim.x + threadIdx.x) >> 4;
  int lane = threadIdx.x & 15;
  if (g >= n) return;
  uint4 u = S[(size_t)g * 16 + lane];
  float a0 = bfl(u.x), a1 = bfh(u.x), a2 = bfl(u.y), a3 = bfh(u.y);
  float a4 = bfl(u.z), a5 = bfh(u.z), a6 = bfl(u.w), a7 = bfh(u.w);
  int e0 = rowp[g], e1 = rowp[g + 1];
  for (int e = e0; e < e1; e++) {
    int s = col[e];
    uint4 v = S[(size_t)s * 16 + lane];
    a0 += bfl(v.x); a1 += bfh(v.x); a2 += bfl(v.y); a3 += bfh(v.y);
    a4 += bfl(v.z); a5 += bfh(v.z); a6 += bfl(v.w); a7 += bfh(v.w);
  }
  float d = dinv[g];
  uint4 o;
  o.x = pk2(a0 * d, a1 * d); o.y = pk2(a2 * d, a3 * d);
  o.z = pk2(a4 * d, a5 * d); o.w = pk2(a6 * d, a7 * d);
  OUT[(size_t)g * 16 + lane] = o;
}

// ---------------- GEMM: Y = relu(A @ W + b) [* dinv if do_scale], A bf16 [n,128] ----------

__global__ __launch_bounds__(256) void gemm_bias_relu(
    const uint4* __restrict__ A, const float* __restrict__ W,
    const float* __restrict__ bias, const float* __restrict__ dinv, int do_scale,
    unsigned short* __restrict__ Y, int n) {
  __shared__ float As[64 * 36];    // 64 rows x 32 k, stride 36
  __shared__ float Ws[32 * 132];   // 32 k x 128 cols, stride 132
  int t = threadIdx.x;
  int row0 = blockIdx.x << 6;
  int rg = t >> 4;
  int cg = t & 15;
  float acc[4][8];
  #pragma unroll
  for (int r = 0; r < 4; r++)
    #pragma unroll
    for (int c = 0; c < 8; c++) acc[r][c] = 0.f;

  for (int kb = 0; kb < 4; kb++) {
    __syncthreads();
    {                                     // A chunk: 64 rows x 32 bf16 (4 uint4 per row)
      int r = t >> 2, q = t & 3;
      int gr = row0 + r;
      uint4 v = make_uint4(0, 0, 0, 0);
      if (gr < n) v = A[(size_t)gr * 16 + kb * 4 + q];
      float4 f0 = make_float4(bfl(v.x), bfh(v.x), bfl(v.y), bfh(v.y));
      float4 f1 = make_float4(bfl(v.z), bfh(v.z), bfl(v.w), bfh(v.w));
      *(float4*)&As[r * 36 + q * 8] = f0;
      *(float4*)&As[r * 36 + q * 8 + 4] = f1;
    }
    for (int i = t; i < 1024; i += 256) { // W chunk: 32 k x 32 f4
      int r = i >> 5, q = i & 31;
      *(float4*)&Ws[r * 132 + q * 4] = ((const float4*)W)[(size_t)(kb * 32 + r) * 32 + q];
    }
    __syncthreads();
    #pragma unroll
    for (int k = 0; k < 32; k += 4) {
      float4 a0 = *(const float4*)&As[(rg * 4 + 0) * 36 + k];
      float4 a1 = *(const float4*)&As[(rg * 4 + 1) * 36 + k];
      float4 a2 = *(const float4*)&As[(rg * 4 + 2) * 36 + k];
      float4 a3 = *(const float4*)&As[(rg * 4 + 3) * 36 + k];
      #pragma unroll
      for (int kk = 0; kk < 4; kk++) {
        float4 w0 = *(const float4*)&Ws[(k + kk) * 132 + cg * 4];
        float4 w1 = *(const float4*)&Ws[(k + kk) * 132 + 64 + cg * 4];
        float av0 = kk == 0 ? a0.x : kk == 1 ? a0.y : kk == 2 ? a0.z : a0.w;
        float av1 = kk == 0 ? a1.x : kk == 1 ? a1.y : kk == 2 ? a1.z : a1.w;
        float av2 = kk == 0 ? a2.x : kk == 1 ? a2.y : kk == 2 ? a2.z : a2.w;
        float av3 = kk == 0 ? a3.x : kk == 1 ? a3.y : kk == 2 ? a3.z : a3.w;
        acc[0][0] += av0 * w0.x; acc[0][1] += av0 * w0.y; acc[0][2] += av0 * w0.z; acc[0][3] += av0 * w0.w;
        acc[0][4] += av0 * w1.x; acc[0][5] += av0 * w1.y; acc[0][6] += av0 * w1.z; acc[0][7] += av0 * w1.w;
        acc[1][0] += av1 * w0.x; acc[1][1] += av1 * w0.y; acc[1][2] += av1 * w0.z; acc[1][3] += av1 * w0.w;
        acc[1][4] += av1 * w1.x; acc[1][5] += av1 * w1.y; acc[1][6] += av1 * w1.z; acc[1][7] += av1 * w1.w;
        acc[2][0] += av2 * w0.x; acc[2][1] += av2 * w0.y; acc[2][2] += av2 * w0.z; acc[2][3] += av2 * w0.w;
        acc[2][4] += av2 * w1.x; acc[2][5] += av2 * w1.y; acc[2][6] += av2 * w1.z; acc[2][7] += av2 * w1.w;
        acc[3][0] += av3 * w0.x; acc[3][1] += av3 * w0.y; acc[3][2] += av3 * w0.z; acc[3][3] += av3 * w0.w;
        acc[3][4] += av3 * w1.x; acc[3][5] += av3 * w1.y; acc[3][6] += av3 * w1.z; acc[3][7] += av3 * w1.w;
      }
    }
  }
  float4 b0v = *(const float4*)&bias[cg * 4];
  float4 b1v = *(const float4*)&bias[64 + cg * 4];
  #pragma unroll
  for (int r = 0; r < 4; r++) {
    int gr = row0 + rg * 4 + r;
    if (gr < n) {
      float sc = do_scale ? dinv[gr] : 1.0f;
      float o0 = fmaxf(acc[r][0] + b0v.x, 0.f) * sc;
      float o1 = fmaxf(acc[r][1] + b0v.y, 0.f) * sc;
      float o2 = fmaxf(acc[r][2] + b0v.z, 0.f) * sc;
      float o3 = fmaxf(acc[r][3] + b0v.w, 0.f) * sc;
      float o4 = fmaxf(acc[r][4] + b1v.x, 0.f) * sc;
      float o5 = fmaxf(acc[r][5] + b1v.y, 0.f) * sc;
      float o6 = fmaxf(acc[r][6] + b1v.z, 0.f) * sc;
      float o7 = fmaxf(acc[r][7] + b1v.w, 0.f) * sc;
      ushort4 p0; p0.x = f2bf(o0); p0.y = f2bf(o1); p0.z = f2bf(o2); p0.w = f2bf(o3);
      ushort4 p1; p1.x = f2bf(o4); p1.y = f2bf(o5); p1.z = f2bf(o6); p1.w = f2bf(o7);
      ((ushort4*)Y)[(size_t)gr * 32 + cg] = p0;
      ((ushort4*)Y)[(size_t)gr * 32 + 16 + cg] = p1;
    }
  }
}

// ---------------- mean pool (batch sorted, bf16 input) ----------------

__global__ void pool_kernel(const unsigned short* __restrict__ X, const int* __restrict__ batch,
                            float* __restrict__ pooled, float* __restrict__ gcnt, int n) {
  int t = threadIdx.x;             // 128 threads = columns
  int r0 = blockIdx.x * 64;
  if (r0 >= n) return;
  int r1 = min(r0 + 64, n);
  int g = batch[r0];
  float acc = 0.f, cl = 0.f;
  for (int r = r0; r < r1; r++) {
    int gr = batch[r];
    if (gr != g) {
      atomicAdd(&pooled[g * HDIM + t], acc);
      if (t == 0) atomicAdd(&gcnt[g], cl);
      acc = 0.f; cl = 0.f; g = gr;
    }
    acc += __uint_as_float((unsigned)X[(size_t)r * HDIM + t] << 16);
    cl += 1.f;
  }
  atomicAdd(&pooled[g * HDIM + t], acc);
  if (t == 0) atomicAdd(&gcnt[g], cl);
}

// ---------------- classifier head ----------------

__global__ void cls_kernel(const float* __restrict__ pooled, const float* __restrict__ gcnt,
                           const float* __restrict__ Wc1, const float* __restrict__ bc1,
                           const float* __restrict__ Wc2, const float* __restrict__ bc2,
                           float* __restrict__ out) {
  __shared__ float p[HDIM];
  __shared__ float r0s[HDIM], r1s[HDIM];
  int g = blockIdx.x, t = threadIdx.x;
  float c = fmaxf(gcnt[g], 1.0f);
  p[t] = pooled[g * HDIM + t] / c;
  __syncthreads();
  float acc = bc1[t];
  for (int k = 0; k < HDIM; k++) {
    acc += p[k] * (Wc1[k * HDIM + t] + Wc1[(HDIM + k) * HDIM + t]);
  }
  float h = fmaxf(acc, 0.f);
  r0s[t] = h * Wc2[t * 2 + 0];
  r1s[t] = h * Wc2[t * 2 + 1];
  __syncthreads();
  for (int s2 = 64; s2 > 0; s2 >>= 1) {
    if (t < s2) { r0s[t] += r0s[t + s2]; r1s[t] += r1s[t + s2]; }
    __syncthreads();
  }
  if (t == 0) {
    out[g * 2 + 0] = r0s[0] + bc2[0];
    out[g * 2 + 1] = r1s[0] + bc2[1];
  }
}

// ---------------- launch ----------------

extern "C" void kernel_launch(void* const* d_in, const int* in_sizes, int n_in,
                              void* d_out, int out_size, void* d_ws, size_t ws_size,
                              hipStream_t stream) {
  const float* x   = (const float*)d_in[0];
  const int*   ei  = (const int*)d_in[1];
  const int*   bat = (const int*)d_in[2];
  const float* W0  = (const float*)d_in[3];
  const float* b0  = (const float*)d_in[4];
  const float* W1  = (const float*)d_in[5];
  const float* b1  = (const float*)d_in[6];
  const float* W2  = (const float*)d_in[7];
  const float* b2  = (const float*)d_in[8];
  const float* Wc1 = (const float*)d_in[9];
  const float* bc1 = (const float*)d_in[10];
  const float* Wc2 = (const float*)d_in[11];
  const float* bc2 = (const float*)d_in[12];
  float* out = (float*)d_out;

  int N = in_sizes[0] / HDIM;
  int E = in_sizes[1] / 2;
  const int* src = ei;
  const int* dst = ei + E;

  char* ws = (char*)d_ws;
  size_t off = 0;
  auto alloc = [&](size_t bytes) -> void* {
    void* p = (void*)(ws + off);
    off += (bytes + 511) & ~(size_t)511;
    return p;
  };
  unsigned short* bufS = (unsigned short*)alloc((size_t)N * HDIM * 2);  // scaled state bf16
  unsigned short* bufA = (unsigned short*)alloc((size_t)N * HDIM * 2);  // agg out bf16
  float* dinv   = (float*)alloc((size_t)N * 4);
  int*   cnt    = (int*)alloc((size_t)N * 4);
  int*   rowp   = (int*)alloc((size_t)(N + 1) * 4);
  int*   cur    = (int*)alloc((size_t)N * 4);
  int*   col    = (int*)alloc((size_t)E * 4);
  float* pooled = (float*)alloc((size_t)GCOUNT * HDIM * 4);
  float* gcnt   = (float*)alloc((size_t)GCOUNT * 4);
  int nb = (N + 255) / 256;
  int*   bsum   = (int*)alloc((size_t)nb * 4);

  hipMemsetAsync(cnt, 0, (size_t)N * 4, stream);
  hipMemsetAsync(pooled, 0, (size_t)GCOUNT * HDIM * 4, stream);
  hipMemsetAsync(gcnt, 0, (size_t)GCOUNT * 4, stream);

  int eb8 = (E + 2047) / 2048;   // 8 edges per thread, 256 threads/block
  hist_kernel<<<eb8, 256, 0, stream>>>(dst, cnt, E);
  scan1<<<nb, 256, 0, stream>>>(cnt, rowp, bsum, dinv, N);
  scan2<<<1, 512, 0, stream>>>(bsum, nb);
  scan3<<<(N + 255) / 256, 256, 0, stream>>>(rowp, bsum, cur, N, E);
  fill_kernel<<<eb8, 256, 0, stream>>>(src, dst, cur, col, E);

  int n4 = N * 32;
  prescale_kernel<<<(n4 + 255) / 256, 256, 0, stream>>>(x, dinv, bufS, n4);

  int aggBlocks = (int)(((size_t)N * 16 + 255) / 256);
  int gemmBlocks = (N + 63) / 64;

  agg_bf16<<<aggBlocks, 256, 0, stream>>>((const uint4*)bufS, dinv, rowp, col, (uint4*)bufA, N);
  gemm_bias_relu<<<gemmBlocks, 256, 0, stream>>>((const uint4*)bufA, W0, b0, dinv, 1, bufS, N);

  agg_bf16<<<aggBlocks, 256, 0, stream>>>((const uint4*)bufS, dinv, rowp, col, (uint4*)bufA, N);
  gemm_bias_relu<<<gemmBlocks, 256, 0, stream>>>((const uint4*)bufA, W1, b1, dinv, 1, bufS, N);

  agg_bf16<<<aggBlocks, 256, 0, stream>>>((const uint4*)bufS, dinv, rowp, col, (uint4*)bufA, N);
  gemm_bias_relu<<<gemmBlocks, 256, 0, stream>>>((const uint4*)bufA, W2, b2, dinv, 0, bufS, N);

  pool_kernel<<<(N + 63) / 64, 128, 0, stream>>>(bufS, bat, pooled, gcnt, N);
  cls_kernel<<<GCOUNT, HDIM, 0, stream>>>(pooled, gcnt, Wc1, bc1, Wc2, bc2, out);
}

// Round 4
// 660.599 us; speedup vs baseline: 1.3819x; 1.0415x over previous
//
#include <hip/hip_runtime.h>

#define HDIM 128
#define GCOUNT 64

// ---- bf16 helpers (manual, RNE) ----
__device__ __forceinline__ float bfl(unsigned u) { return __uint_as_float(u << 16); }
__device__ __forceinline__ float bfh(unsigned u) { return __uint_as_float(u & 0xffff0000u); }
__device__ __forceinline__ unsigned short f2bf(float f) {
  unsigned u = __float_as_uint(f);
  unsigned r = (u + 0x7fffu + ((u >> 16) & 1u)) >> 16;
  return (unsigned short)r;
}
__device__ __forceinline__ unsigned pk2(float a, float b) {
  return (unsigned)f2bf(a) | ((unsigned)f2bf(b) << 16);
}

typedef __attribute__((ext_vector_type(8))) short short8;
typedef __attribute__((ext_vector_type(4))) float f32x4;

// ---------------- degree / CSR build ----------------
// hist: per-edge atomic returns a stable unique rank within the dst bucket.

__global__ void hist_kernel(const int* __restrict__ dst, int* __restrict__ cnt,
                            int* __restrict__ rank, int E) {
  int i0 = blockIdx.x * 2048 + threadIdx.x;
  #pragma unroll
  for (int j = 0; j < 8; j++) {
    int e = i0 + j * 256;
    if (e < E) rank[e] = atomicAdd(&cnt[dst[e]], 1);
  }
}

__global__ void scan1(const int* __restrict__ cnt, int* __restrict__ row_ptr,
                      int* __restrict__ bsum, float* __restrict__ dinv, int n) {
  __shared__ int sh[256];
  int t = threadIdx.x;
  int i = blockIdx.x * 256 + t;
  int v = (i < n) ? cnt[i] : 0;
  if (i < n) dinv[i] = rsqrtf((float)v + 1.0f);
  sh[t] = v;
  __syncthreads();
  for (int off = 1; off < 256; off <<= 1) {
    int u = (t >= off) ? sh[t - off] : 0;
    __syncthreads();
    sh[t] += u;
    __syncthreads();
  }
  if (i < n) row_ptr[i] = sh[t] - v;
  if (t == 255) bsum[blockIdx.x] = sh[255];
}

__global__ void scan2(int* __restrict__ bsum, int nb) {
  __shared__ int sh[512];
  int t = threadIdx.x;
  int v = (t < nb) ? bsum[t] : 0;
  sh[t] = v;
  __syncthreads();
  for (int off = 1; off < 512; off <<= 1) {
    int u = (t >= off) ? sh[t - off] : 0;
    __syncthreads();
    sh[t] += u;
    __syncthreads();
  }
  if (t < nb) bsum[t] = sh[t] - v;
}

__global__ void scan3(int* __restrict__ row_ptr, const int* __restrict__ bsum, int n, int E) {
  int i = blockIdx.x * blockDim.x + threadIdx.x;
  if (i < n) row_ptr[i] += bsum[i >> 8];
  if (i == 0) row_ptr[n] = E;
}

// atomic-free fill: slot = rowp[dst] + rank
__global__ void fill2_kernel(const int* __restrict__ src, const int* __restrict__ dst,
                             const int* __restrict__ rank, const int* __restrict__ rowp,
                             int* __restrict__ col, int E) {
  int i0 = blockIdx.x * 2048 + threadIdx.x;
  #pragma unroll
  for (int j = 0; j < 8; j++) {
    int e = i0 + j * 256;
    if (e < E) col[rowp[dst[e]] + rank[e]] = src[e];
  }
}

// ---------------- weight prep: WT = transpose(W) as bf16 hi+lo split ----------------

__global__ void prep_wt(const float* __restrict__ W, unsigned short* __restrict__ hi,
                        unsigned short* __restrict__ lo) {
  int idx = blockIdx.x * 256 + threadIdx.x;   // 64 blocks x 256 = 16384
  int k = idx >> 7, nn = idx & 127;
  float w = W[idx];
  unsigned short h = f2bf(w);
  float hf = __uint_as_float((unsigned)h << 16);
  unsigned short l = f2bf(w - hf);
  hi[nn * 128 + k] = h;
  lo[nn * 128 + k] = l;
}

// ---------------- prescale: S0[i] = bf16(dinv_i * x_i) ----------------

__global__ void prescale_kernel(const float* __restrict__ x, const float* __restrict__ dinv,
                                unsigned short* __restrict__ S, int n4) {
  int i = blockIdx.x * blockDim.x + threadIdx.x;
  if (i >= n4) return;
  float4 v = ((const float4*)x)[i];
  float d = dinv[i >> 5];
  ushort4 o;
  o.x = f2bf(v.x * d); o.y = f2bf(v.y * d); o.z = f2bf(v.z * d); o.w = f2bf(v.w * d);
  ((ushort4*)S)[i] = o;
}

// ---------------- aggregation (scaled bf16 state) ----------------

__global__ void agg_bf16(const uint4* __restrict__ S, const float* __restrict__ dinv,
                         const int* __restrict__ rowp, const int* __restrict__ col,
                         uint4* __restrict__ OUT, int n) {
  int g = (blockIdx.x * blockDim.x + threadIdx.x) >> 4;
  int lane = threadIdx.x & 15;
  if (g >= n) return;
  uint4 u = S[(size_t)g * 16 + lane];
  float a0 = bfl(u.x), a1 = bfh(u.x), a2 = bfl(u.y), a3 = bfh(u.y);
  float a4 = bfl(u.z), a5 = bfh(u.z), a6 = bfl(u.w), a7 = bfh(u.w);
  int e0 = rowp[g], e1 = rowp[g + 1];
  for (int e = e0; e < e1; e++) {
    int s = col[e];
    uint4 v = S[(size_t)s * 16 + lane];
    a0 += bfl(v.x); a1 += bfh(v.x); a2 += bfl(v.y); a3 += bfh(v.y);
    a4 += bfl(v.z); a5 += bfh(v.z); a6 += bfl(v.w); a7 += bfh(v.w);
  }
  float d = dinv[g];
  uint4 o;
  o.x = pk2(a0 * d, a1 * d); o.y = pk2(a2 * d, a3 * d);
  o.z = pk2(a4 * d, a5 * d); o.w = pk2(a6 * d, a7 * d);
  OUT[(size_t)g * 16 + lane] = o;
}

// ---------------- MFMA GEMM: Y = relu(A @ W + b) [* dinv], A bf16 [n,128] ------------
// Wave = 16 rows x 128 cols. A-frag A[m=lane&15][k=quad*8+j] = uint4 from row-major A.
// B-frag from WT[n][k] (transposed, bf16 hi+lo). C/D: row=quad*4+reg, col=lane&15.

__global__ __launch_bounds__(256) void gemm_mfma(
    const uint4* __restrict__ A, const uint4* __restrict__ WThi, const uint4* __restrict__ WTlo,
    const float* __restrict__ bias, const float* __restrict__ dinv, int do_scale,
    unsigned short* __restrict__ Y, int n) {
  int t = threadIdx.x;
  int lane = t & 63, wv = t >> 6;
  int m = lane & 15, quad = lane >> 4;
  int row0 = blockIdx.x * 64 + wv * 16;
  int arow = row0 + m;
  f32x4 acc[8];
  #pragma unroll
  for (int i = 0; i < 8; i++) acc[i] = (f32x4){0.f, 0.f, 0.f, 0.f};
  #pragma unroll
  for (int kb = 0; kb < 4; kb++) {
    uint4 av = (arow < n) ? A[(size_t)arow * 16 + kb * 4 + quad] : make_uint4(0, 0, 0, 0);
    short8 af = __builtin_bit_cast(short8, av);
    #pragma unroll
    for (int nt = 0; nt < 8; nt++) {
      int colr = nt * 16 + m;
      uint4 bh = WThi[(size_t)colr * 16 + kb * 4 + quad];
      uint4 bl = WTlo[(size_t)colr * 16 + kb * 4 + quad];
      acc[nt] = __builtin_amdgcn_mfma_f32_16x16x32_bf16(af, __builtin_bit_cast(short8, bh), acc[nt], 0, 0, 0);
      acc[nt] = __builtin_amdgcn_mfma_f32_16x16x32_bf16(af, __builtin_bit_cast(short8, bl), acc[nt], 0, 0, 0);
    }
  }
  #pragma unroll
  for (int r = 0; r < 4; r++) {
    int grow = row0 + quad * 4 + r;
    if (grow < n) {
      float sc = do_scale ? dinv[grow] : 1.0f;
      #pragma unroll
      for (int nt = 0; nt < 8; nt++) {
        int colr = nt * 16 + m;
        float v = fmaxf(acc[nt][r] + bias[colr], 0.f) * sc;
        Y[(size_t)grow * 128 + colr] = f2bf(v);
      }
    }
  }
}

// ---------------- mean pool (batch sorted, bf16 input) ----------------

__global__ void pool_kernel(const unsigned short* __restrict__ X, const int* __restrict__ batch,
                            float* __restrict__ pooled, float* __restrict__ gcnt, int n) {
  int t = threadIdx.x;             // 128 threads = columns
  int r0 = blockIdx.x * 64;
  if (r0 >= n) return;
  int r1 = min(r0 + 64, n);
  int g = batch[r0];
  float acc = 0.f, cl = 0.f;
  for (int r = r0; r < r1; r++) {
    int gr = batch[r];
    if (gr != g) {
      atomicAdd(&pooled[g * HDIM + t], acc);
      if (t == 0) atomicAdd(&gcnt[g], cl);
      acc = 0.f; cl = 0.f; g = gr;
    }
    acc += __uint_as_float((unsigned)X[(size_t)r * HDIM + t] << 16);
    cl += 1.f;
  }
  atomicAdd(&pooled[g * HDIM + t], acc);
  if (t == 0) atomicAdd(&gcnt[g], cl);
}

// ---------------- classifier head ----------------

__global__ void cls_kernel(const float* __restrict__ pooled, const float* __restrict__ gcnt,
                           const float* __restrict__ Wc1, const float* __restrict__ bc1,
                           const float* __restrict__ Wc2, const float* __restrict__ bc2,
                           float* __restrict__ out) {
  __shared__ float p[HDIM];
  __shared__ float r0s[HDIM], r1s[HDIM];
  int g = blockIdx.x, t = threadIdx.x;
  float c = fmaxf(gcnt[g], 1.0f);
  p[t] = pooled[g * HDIM + t] / c;
  __syncthreads();
  float acc = bc1[t];
  for (int k = 0; k < HDIM; k++) {
    acc += p[k] * (Wc1[k * HDIM + t] + Wc1[(HDIM + k) * HDIM + t]);
  }
  float h = fmaxf(acc, 0.f);
  r0s[t] = h * Wc2[t * 2 + 0];
  r1s[t] = h * Wc2[t * 2 + 1];
  __syncthreads();
  for (int s2 = 64; s2 > 0; s2 >>= 1) {
    if (t < s2) { r0s[t] += r0s[t + s2]; r1s[t] += r1s[t + s2]; }
    __syncthreads();
  }
  if (t == 0) {
    out[g * 2 + 0] = r0s[0] + bc2[0];
    out[g * 2 + 1] = r1s[0] + bc2[1];
  }
}

// ---------------- launch ----------------

extern "C" void kernel_launch(void* const* d_in, const int* in_sizes, int n_in,
                              void* d_out, int out_size, void* d_ws, size_t ws_size,
                              hipStream_t stream) {
  const float* x   = (const float*)d_in[0];
  const int*   ei  = (const int*)d_in[1];
  const int*   bat = (const int*)d_in[2];
  const float* W0  = (const float*)d_in[3];
  const float* b0  = (const float*)d_in[4];
  const float* W1  = (const float*)d_in[5];
  const float* b1  = (const float*)d_in[6];
  const float* W2  = (const float*)d_in[7];
  const float* b2  = (const float*)d_in[8];
  const float* Wc1 = (const float*)d_in[9];
  const float* bc1 = (const float*)d_in[10];
  const float* Wc2 = (const float*)d_in[11];
  const float* bc2 = (const float*)d_in[12];
  float* out = (float*)d_out;

  int N = in_sizes[0] / HDIM;
  int E = in_sizes[1] / 2;
  const int* src = ei;
  const int* dst = ei + E;

  char* ws = (char*)d_ws;
  size_t off = 0;
  auto alloc = [&](size_t bytes) -> void* {
    void* p = (void*)(ws + off);
    off += (bytes + 511) & ~(size_t)511;
    return p;
  };
  unsigned short* bufS = (unsigned short*)alloc((size_t)N * HDIM * 2);  // scaled state bf16
  unsigned short* bufA = (unsigned short*)alloc((size_t)N * HDIM * 2);  // agg out bf16
  float* dinv   = (float*)alloc((size_t)N * 4);
  int*   cnt    = (int*)alloc((size_t)N * 4);
  int*   rowp   = (int*)alloc((size_t)(N + 1) * 4);
  int*   col    = (int*)alloc((size_t)E * 4);
  int*   rank   = (int*)alloc((size_t)E * 4);
  float* pooled = (float*)alloc((size_t)GCOUNT * HDIM * 4);
  float* gcnt   = (float*)alloc((size_t)GCOUNT * 4);
  unsigned short* wt_hi[3], *wt_lo[3];
  for (int i = 0; i < 3; i++) {
    wt_hi[i] = (unsigned short*)alloc(HDIM * HDIM * 2);
    wt_lo[i] = (unsigned short*)alloc(HDIM * HDIM * 2);
  }
  int nb = (N + 255) / 256;
  int* bsum = (int*)alloc((size_t)nb * 4);

  hipMemsetAsync(cnt, 0, (size_t)N * 4, stream);
  hipMemsetAsync(pooled, 0, (size_t)GCOUNT * HDIM * 4, stream);
  hipMemsetAsync(gcnt, 0, (size_t)GCOUNT * 4, stream);

  prep_wt<<<64, 256, 0, stream>>>(W0, wt_hi[0], wt_lo[0]);
  prep_wt<<<64, 256, 0, stream>>>(W1, wt_hi[1], wt_lo[1]);
  prep_wt<<<64, 256, 0, stream>>>(W2, wt_hi[2], wt_lo[2]);

  int eb8 = (E + 2047) / 2048;   // 8 edges per thread, 256 threads/block
  hist_kernel<<<eb8, 256, 0, stream>>>(dst, cnt, rank, E);
  scan1<<<nb, 256, 0, stream>>>(cnt, rowp, bsum, dinv, N);
  scan2<<<1, 512, 0, stream>>>(bsum, nb);
  scan3<<<(N + 255) / 256, 256, 0, stream>>>(rowp, bsum, N, E);
  fill2_kernel<<<eb8, 256, 0, stream>>>(src, dst, rank, rowp, col, E);

  int n4 = N * 32;
  prescale_kernel<<<(n4 + 255) / 256, 256, 0, stream>>>(x, dinv, bufS, n4);

  int aggBlocks = (int)(((size_t)N * 16 + 255) / 256);
  int gemmBlocks = (N + 63) / 64;

  agg_bf16<<<aggBlocks, 256, 0, stream>>>((const uint4*)bufS, dinv, rowp, col, (uint4*)bufA, N);
  gemm_mfma<<<gemmBlocks, 256, 0, stream>>>((const uint4*)bufA, (const uint4*)wt_hi[0],
      (const uint4*)wt_lo[0], b0, dinv, 1, bufS, N);

  agg_bf16<<<aggBlocks, 256, 0, stream>>>((const uint4*)bufS, dinv, rowp, col, (uint4*)bufA, N);
  gemm_mfma<<<gemmBlocks, 256, 0, stream>>>((const uint4*)bufA, (const uint4*)wt_hi[1],
      (const uint4*)wt_lo[1], b1, dinv, 1, bufS, N);

  agg_bf16<<<aggBlocks, 256, 0, stream>>>((const uint4*)bufS, dinv, rowp, col, (uint4*)bufA, N);
  gemm_mfma<<<gemmBlocks, 256, 0, stream>>>((const uint4*)bufA, (const uint4*)wt_hi[2],
      (const uint4*)wt_lo[2], b2, dinv, 0, bufS, N);

  pool_kernel<<<(N + 63) / 64, 128, 0, stream>>>(bufS, bat, pooled, gcnt, N);
  cls_kernel<<<GCOUNT, HDIM, 0, stream>>>(pooled, gcnt, Wc1, bc1, Wc2, bc2, out);
}